// Round 3
// baseline (299.032 us; speedup 1.0000x reference)
//
#include <hip/hip_runtime.h>

#define NN 8192
#define FIN 512
#define FOUT 256
#define JS 8
#define STRIP (NN / JS)   // 1024 j per split
#define NSTEP (STRIP / 32)

typedef _Float16 f16;
typedef __attribute__((ext_vector_type(8))) _Float16 f16x8;
typedef __attribute__((ext_vector_type(4))) _Float16 f16x4;
typedef __attribute__((ext_vector_type(4))) float f32x4;
typedef __attribute__((ext_vector_type(16))) float f32x16;
typedef __attribute__((ext_vector_type(4))) int i32x4;

__device__ __forceinline__ float lrelu(float x) { return fmaxf(x, 0.2f * x); }

// ---- prep h: f32 -> f16 hi/lo split (for accurate split-f16 GEMM)
__global__ void k_prep_h(const float* __restrict__ h, f16* __restrict__ hh,
                         f16* __restrict__ hl) {
  int idx = (blockIdx.x * 256 + threadIdx.x) * 4;
  f32x4 v = *(const f32x4*)(h + idx);
  f16x4 hi, lo;
#pragma unroll
  for (int i = 0; i < 4; ++i) {
    f16 a = (f16)v[i];
    hi[i] = a;
    lo[i] = (f16)(v[i] - (float)a);
  }
  *(f16x4*)(hh + idx) = hi;
  *(f16x4*)(hl + idx) = lo;
}

// ---- prep W: f32 [FIN][FOUT] -> f16 hi/lo transposed [FOUT][FIN]
__global__ void k_prep_w(const float* __restrict__ W, f16* __restrict__ wth,
                         f16* __restrict__ wtl) {
  int id = blockIdx.x * 256 + threadIdx.x;  // 131072 total
  int c = id >> 9, k = id & 511;
  float v = W[k * FOUT + c];
  f16 a = (f16)v;
  wth[c * FIN + k] = a;
  wtl[c * FIN + k] = (f16)(v - (float)a);
}

// ---- GEMM1: Wh = h @ W via split-f16 MFMA. Emits WhT (f16, [FOUT][NN]),
// Wh1 = Wh@a1, Wh2 = Wh@a2 (f32). Tile: 32 rows x 256 cols, 4 waves.
__launch_bounds__(256, 2)
__global__ void k_gemm1(const f16* __restrict__ hh, const f16* __restrict__ hl,
                        const f16* __restrict__ wth, const f16* __restrict__ wtl,
                        const float* __restrict__ avec, f16* __restrict__ whT,
                        float* __restrict__ wh1, float* __restrict__ wh2) {
  int i0 = blockIdx.x * 32;
  int tid = threadIdx.x;
  int w = tid >> 6, l = tid & 63, m = l & 15, g = l >> 4;
  f32x4 acc[2][4] = {};
#pragma unroll 1
  for (int k0 = 0; k0 < FIN; k0 += 32) {
    f16x8 ah[2], al[2], bh[4], bl[4];
#pragma unroll
    for (int rf = 0; rf < 2; ++rf) {
      int ro = (i0 + 16 * rf + m) * FIN + k0 + 8 * g;
      ah[rf] = *(const f16x8*)(hh + ro);
      al[rf] = *(const f16x8*)(hl + ro);
    }
#pragma unroll
    for (int cf = 0; cf < 4; ++cf) {
      int co = (64 * w + 16 * cf + m) * FIN + k0 + 8 * g;
      bh[cf] = *(const f16x8*)(wth + co);
      bl[cf] = *(const f16x8*)(wtl + co);
    }
#pragma unroll
    for (int rf = 0; rf < 2; ++rf)
#pragma unroll
      for (int cf = 0; cf < 4; ++cf) {
        acc[rf][cf] = __builtin_amdgcn_mfma_f32_16x16x32_f16(ah[rf], bh[cf], acc[rf][cf], 0, 0, 0);
        acc[rf][cf] = __builtin_amdgcn_mfma_f32_16x16x32_f16(ah[rf], bl[cf], acc[rf][cf], 0, 0, 0);
        acc[rf][cf] = __builtin_amdgcn_mfma_f32_16x16x32_f16(al[rf], bh[cf], acc[rf][cf], 0, 0, 0);
      }
  }
  __shared__ float tile[32][FOUT + 1];
#pragma unroll
  for (int rf = 0; rf < 2; ++rf)
#pragma unroll
    for (int cf = 0; cf < 4; ++cf)
#pragma unroll
      for (int r = 0; r < 4; ++r)
        tile[16 * rf + 4 * g + r][64 * w + 16 * cf + m] = acc[rf][cf][r];
  __syncthreads();
  {  // WhT: one thread per column, 32 rows contiguous
    int c = tid;
    f16x8 vv[4];
#pragma unroll
    for (int r = 0; r < 32; ++r) vv[r >> 3][r & 7] = (f16)tile[r][c];
#pragma unroll
    for (int q = 0; q < 4; ++q) *(f16x8*)(whT + c * NN + i0 + 8 * q) = vv[q];
  }
  {  // Wh1/Wh2 row dots: 8 lanes per row
    int r = tid >> 3, ls = tid & 7;
    float s1 = 0.f, s2 = 0.f;
    for (int c = ls; c < FOUT; c += 8) {
      float v = tile[r][c];
      s1 = fmaf(v, avec[c], s1);
      s2 = fmaf(v, avec[FOUT + c], s2);
    }
#pragma unroll
    for (int off = 1; off < 8; off <<= 1) {
      s1 += __shfl_xor(s1, off);
      s2 += __shfl_xor(s2, off);
    }
    if (ls == 0) {
      wh1[i0 + r] = s1;
      wh2[i0 + r] = s2;
    }
  }
}

// ---- global max of Wh2 (safe softmax shift bound)
__global__ void k_max2(const float* __restrict__ wh2, float* __restrict__ m2) {
  int t = threadIdx.x;
  float mx = -1e30f;
  for (int i = t; i < NN; i += 256) mx = fmaxf(mx, wh2[i]);
#pragma unroll
  for (int off = 1; off < 64; off <<= 1) mx = fmaxf(mx, __shfl_xor(mx, off));
  __shared__ float sm[4];
  if ((t & 63) == 0) sm[t >> 6] = mx;
  __syncthreads();
  if (t == 0) m2[0] = fmaxf(fmaxf(sm[0], sm[1]), fmaxf(sm[2], sm[3]));
}

// ---- fused masked-softmax + PV, barrier-free, in-register P, 32x32x16 MFMA.
// Grid: (NN/64 row-blocks) x JS j-splits (js = bx&7 -> one whT strip per XCD).
// Block: 4 waves = 2 row-groups x 2 col-groups; wave = 32 rows x 128 cols.
// Lane l: A-row = l&31, k-half = l>>5. acc[4] f32x16 = 64 AGPR.
__launch_bounds__(256, 3)
__global__ void k_attn(const int* __restrict__ adj, const f16* __restrict__ whT,
                       const float* __restrict__ wh1, const float* __restrict__ wh2,
                       const float* __restrict__ m2g, float* __restrict__ accP,
                       float* __restrict__ zP) {
  int bx = blockIdx.x;
  int js = bx & (JS - 1), rb = bx >> 3;
  int i0 = rb * 64;
  int jbase = js * STRIP;
  int tid = threadIdx.x;
  int w = tid >> 6, l = tid & 63;
  int rg = w >> 1, cg = w & 1;
  int lr = l & 31, hi = l >> 5;
  int row = i0 + rg * 32 + lr;
  float M2 = m2g[0];
  float w1 = wh1[row];
  float mrow = lrelu(w1 + M2);

  f32x16 acc[4] = {};
  float zacc = 0.f;

  const int* arow = adj + (size_t)row * NN + jbase + 8 * hi;
  const float* w2p = wh2 + jbase + 8 * hi;
  const f16* bp = whT + (size_t)(cg * 128 + lr) * NN + jbase + 8 * hi;

  // adj prefetch depth-1: a[q] covers j-offsets {0..3,4..7,16..19,20..23}
  i32x4 a[4], an[4];
#pragma unroll
  for (int q = 0; q < 4; ++q)
    a[q] = *(const i32x4*)(arow + 16 * (q >> 1) + 4 * (q & 1));

#pragma unroll 1
  for (int t = 0; t < NSTEP; ++t) {
    int cur = t * 32;
    int nxt = (t + 1 < NSTEP) ? cur + 32 : cur;
    // issue next step's adj (HBM latency hides under this step)
#pragma unroll
    for (int q = 0; q < 4; ++q)
      an[q] = *(const i32x4*)(arow + nxt + 16 * (q >> 1) + 4 * (q & 1));
    // w2 for this step (L1-resident, 4 KB strip)
    f32x4 wv[4];
#pragma unroll
    for (int q = 0; q < 4; ++q)
      wv[q] = *(const f32x4*)(w2p + cur + 16 * (q >> 1) + 4 * (q & 1));
    // P-gen: af[kb][e] = P[row][cur + 16*kb + 8*hi + e]
    f16x8 af[2];
#pragma unroll
    for (int kb = 0; kb < 2; ++kb)
#pragma unroll
      for (int e = 0; e < 8; ++e) {
        int q = 2 * kb + (e >> 2);
        float s = w1 + wv[q][e & 3];
        float sc = fmaxf(s, 0.2f * s);
        float p = (a[q][e & 3] > 0) ? __expf(sc - mrow) : 0.f;
        zacc += p;
        af[kb][e] = (f16)p;
      }
    // B from whT (L2-resident strip) + MFMA
#pragma unroll
    for (int kb = 0; kb < 2; ++kb) {
      f16x8 bf[4];
#pragma unroll
      for (int cf = 0; cf < 4; ++cf)
        bf[cf] = *(const f16x8*)(bp + (size_t)cf * 32 * NN + cur + 16 * kb);
#pragma unroll
      for (int cf = 0; cf < 4; ++cf)
        acc[cf] = __builtin_amdgcn_mfma_f32_32x32x16_f16(af[kb], bf[cf], acc[cf], 0, 0, 0);
    }
#pragma unroll
    for (int q = 0; q < 4; ++q) a[q] = an[q];
  }

  // Z: sum the two k-halves (lane l and l+32 hold same row)
  zacc += __shfl_xor(zacc, 32);
  if (cg == 0 && hi == 0) zP[(size_t)js * NN + row] = zacc;

  // partial accumulator out (f32, nontemporal). C/D: col=lane&31,
  // row=(reg&3)+8*(reg>>2)+4*(lane>>5)
  float* ap = accP + (size_t)js * NN * FOUT;
#pragma unroll
  for (int cf = 0; cf < 4; ++cf)
#pragma unroll
    for (int r = 0; r < 16; ++r) {
      int grow = i0 + rg * 32 + 4 * hi + (r & 3) + 8 * (r >> 2);
      int gcol = cg * 128 + 32 * cf + lr;
      __builtin_nontemporal_store(acc[cf][r], ap + (size_t)grow * FOUT + gcol);
    }
}

// ---- combine JS partials, divide by Z, elu
__global__ void k_combine(const float* __restrict__ accP, const float* __restrict__ zP,
                          float* __restrict__ out) {
  int id = blockIdx.x * 256 + threadIdx.x;
  size_t idx = (size_t)id * 4;
  int row = (int)(idx >> 8);
  f32x4 s = {};
#pragma unroll
  for (int p = 0; p < JS; ++p) {
    f32x4 v = __builtin_nontemporal_load((const f32x4*)(accP + (size_t)p * NN * FOUT + idx));
    s[0] += v[0]; s[1] += v[1]; s[2] += v[2]; s[3] += v[3];
  }
  float z = 0.f;
#pragma unroll
  for (int p = 0; p < JS; ++p) z += zP[(size_t)p * NN + row];
  float inv = (z > 0.f) ? 1.f / z : 0.f;
  f32x4 o;
#pragma unroll
  for (int i = 0; i < 4; ++i) {
    float x = s[i] * inv;
    o[i] = (x > 0.f) ? x : expm1f(x);
  }
  *(f32x4*)(out + idx) = o;
}

extern "C" void kernel_launch(void* const* d_in, const int* in_sizes, int n_in,
                              void* d_out, int out_size, void* d_ws, size_t ws_size,
                              hipStream_t stream) {
  const float* h = (const float*)d_in[0];
  const int* adj = (const int*)d_in[1];
  const float* W = (const float*)d_in[2];
  const float* a = (const float*)d_in[3];
  (void)in_sizes; (void)n_in; (void)out_size; (void)ws_size;

  char* ws = (char*)d_ws;
  size_t off = 0;
  auto alloc = [&](size_t bytes) {
    void* p = ws + off;
    off = (off + bytes + 255) & ~(size_t)255;
    return p;
  };
  // accP is only written by k_attn (after gemm1 is done with the prep
  // buffers), so hh/hl/wth/wtl alias the front of the accP region.
  float* accP = (float*)alloc((size_t)JS * NN * FOUT * 4);  // 64 MB
  f16* whT = (f16*)alloc((size_t)FOUT * NN * 2);
  float* wh1 = (float*)alloc((size_t)NN * 4);
  float* wh2 = (float*)alloc((size_t)NN * 4);
  float* m2 = (float*)alloc(256);
  float* zP = (float*)alloc((size_t)JS * NN * 4);
  // aliased prep buffers (lifetime ends when k_gemm1 completes)
  char* pb = (char*)accP;
  f16* hh = (f16*)pb;
  f16* hl = (f16*)(pb + (size_t)NN * FIN * 2);
  f16* wth = (f16*)(pb + (size_t)NN * FIN * 4);
  f16* wtl = (f16*)(pb + (size_t)NN * FIN * 4 + (size_t)FOUT * FIN * 2);

  k_prep_h<<<NN * FIN / 1024, 256, 0, stream>>>(h, hh, hl);
  k_prep_w<<<FIN * FOUT / 256, 256, 0, stream>>>(W, wth, wtl);
  k_gemm1<<<NN / 32, 256, 0, stream>>>(hh, hl, wth, wtl, a, whT, wh1, wh2);
  k_max2<<<1, 256, 0, stream>>>(wh2, m2);
  k_attn<<<(NN / 64) * JS, 256, 0, stream>>>(adj, whT, wh1, wh2, m2, accP, zP);
  k_combine<<<NN * FOUT / 1024, 256, 0, stream>>>(accP, zP, (float*)d_out);
}

// Round 4
// 189.150 us; speedup vs baseline: 1.5809x; 1.5809x over previous
//
#include <hip/hip_runtime.h>

#define NN 8192
#define FIN 512
#define FOUT 256
#define JS 8
#define STRIP 1024   // j per block strip
#define NSTEP 32     // 32 j per step

typedef _Float16 f16;
typedef __attribute__((ext_vector_type(8))) _Float16 f16x8;
typedef __attribute__((ext_vector_type(4))) _Float16 f16x4;
typedef __attribute__((ext_vector_type(4))) float f32x4;
typedef __attribute__((ext_vector_type(16))) float f32x16;
typedef __attribute__((ext_vector_type(4))) int i32x4;

__device__ __forceinline__ float lrelu(float x) { return fmaxf(x, 0.2f * x); }

// ---- prep h: f32 -> f16 hi/lo split (for accurate split-f16 GEMM)
__global__ void k_prep_h(const float* __restrict__ h, f16* __restrict__ hh,
                         f16* __restrict__ hl) {
  int idx = (blockIdx.x * 256 + threadIdx.x) * 4;
  f32x4 v = *(const f32x4*)(h + idx);
  f16x4 hi, lo;
#pragma unroll
  for (int i = 0; i < 4; ++i) {
    f16 a = (f16)v[i];
    hi[i] = a;
    lo[i] = (f16)(v[i] - (float)a);
  }
  *(f16x4*)(hh + idx) = hi;
  *(f16x4*)(hl + idx) = lo;
}

// ---- prep W: f32 [FIN][FOUT] -> f16 hi/lo transposed [FOUT][FIN]
__global__ void k_prep_w(const float* __restrict__ W, f16* __restrict__ wth,
                         f16* __restrict__ wtl) {
  int id = blockIdx.x * 256 + threadIdx.x;
  int c = id >> 9, k = id & 511;
  float v = W[k * FOUT + c];
  f16 a = (f16)v;
  wth[c * FIN + k] = a;
  wtl[c * FIN + k] = (f16)(v - (float)a);
}

// ---- GEMM1: Wh = h @ W via split-f16 MFMA. Emits whT16 (f16, tiled
// [i/16][256 c][16 i]), Wh1, Wh2 (f32). Tile: 32 rows x 256 cols, 4 waves.
__launch_bounds__(256, 2)
__global__ void k_gemm1(const f16* __restrict__ hh, const f16* __restrict__ hl,
                        const f16* __restrict__ wth, const f16* __restrict__ wtl,
                        const float* __restrict__ avec, f16* __restrict__ whT16,
                        float* __restrict__ wh1, float* __restrict__ wh2) {
  int i0 = blockIdx.x * 32;
  int tid = threadIdx.x;
  int w = tid >> 6, l = tid & 63, m = l & 15, g = l >> 4;
  f32x4 acc[2][4] = {};
#pragma unroll 1
  for (int k0 = 0; k0 < FIN; k0 += 32) {
    f16x8 ah[2], al[2], bh[4], bl[4];
#pragma unroll
    for (int rf = 0; rf < 2; ++rf) {
      int ro = (i0 + 16 * rf + m) * FIN + k0 + 8 * g;
      ah[rf] = *(const f16x8*)(hh + ro);
      al[rf] = *(const f16x8*)(hl + ro);
    }
#pragma unroll
    for (int cf = 0; cf < 4; ++cf) {
      int co = (64 * w + 16 * cf + m) * FIN + k0 + 8 * g;
      bh[cf] = *(const f16x8*)(wth + co);
      bl[cf] = *(const f16x8*)(wtl + co);
    }
#pragma unroll
    for (int rf = 0; rf < 2; ++rf)
#pragma unroll
      for (int cf = 0; cf < 4; ++cf) {
        acc[rf][cf] = __builtin_amdgcn_mfma_f32_16x16x32_f16(ah[rf], bh[cf], acc[rf][cf], 0, 0, 0);
        acc[rf][cf] = __builtin_amdgcn_mfma_f32_16x16x32_f16(ah[rf], bl[cf], acc[rf][cf], 0, 0, 0);
        acc[rf][cf] = __builtin_amdgcn_mfma_f32_16x16x32_f16(al[rf], bh[cf], acc[rf][cf], 0, 0, 0);
      }
  }
  __shared__ float tile[32][FOUT + 1];
#pragma unroll
  for (int rf = 0; rf < 2; ++rf)
#pragma unroll
    for (int cf = 0; cf < 4; ++cf)
#pragma unroll
      for (int r = 0; r < 4; ++r)
        tile[16 * rf + 4 * g + r][64 * w + 16 * cf + m] = acc[rf][cf][r];
  __syncthreads();
  {  // whT16 tiled write: thread = column c, 32 rows = 2 j16-groups
    int c = tid;
    f16x8 vv[4];
#pragma unroll
    for (int r = 0; r < 32; ++r) vv[r >> 3][r & 7] = (f16)tile[r][c];
    size_t base = ((size_t)(i0 >> 4) * 256 + c) * 16;
    *(f16x8*)(whT16 + base) = vv[0];
    *(f16x8*)(whT16 + base + 8) = vv[1];
    *(f16x8*)(whT16 + base + 4096) = vv[2];
    *(f16x8*)(whT16 + base + 4096 + 8) = vv[3];
  }
  {  // Wh1/Wh2 row dots: 8 lanes per row
    int r = tid >> 3, ls = tid & 7;
    float s1 = 0.f, s2 = 0.f;
    for (int c = ls; c < FOUT; c += 8) {
      float v = tile[r][c];
      s1 = fmaf(v, avec[c], s1);
      s2 = fmaf(v, avec[FOUT + c], s2);
    }
#pragma unroll
    for (int off = 1; off < 8; off <<= 1) {
      s1 += __shfl_xor(s1, off);
      s2 += __shfl_xor(s2, off);
    }
    if (ls == 0) {
      wh1[i0 + r] = s1;
      wh2[i0 + r] = s2;
    }
  }
}

// ---- global max of Wh2 (safe softmax shift bound)
__global__ void k_max2(const float* __restrict__ wh2, float* __restrict__ m2) {
  int t = threadIdx.x;
  float mx = -1e30f;
  for (int i = t; i < NN; i += 256) mx = fmaxf(mx, wh2[i]);
#pragma unroll
  for (int off = 1; off < 64; off <<= 1) mx = fmaxf(mx, __shfl_xor(mx, off));
  __shared__ float sm[4];
  if ((t & 63) == 0) sm[t >> 6] = mx;
  __syncthreads();
  if (t == 0) m2[0] = fmaxf(fmaxf(sm[0], sm[1]), fmaxf(sm[2], sm[3]));
}

// ---- fused masked-softmax + PV.
// Block: 128 rows x 1024 j strip x 256 cols. 4 waves = 4 col-groups of 64.
// Per step (32 j): adj tile staged coalesced -> LDS (reg-split, 1 step ahead);
// each wave generates P for its 32 rows into LDS (shared by all 4 waves);
// B-fragments are contiguous 1KB loads from whT16. 2 barriers/step.
__launch_bounds__(256, 2)
__global__ void k_attn(const int* __restrict__ adj, const f16* __restrict__ whT16,
                       const float* __restrict__ wh1, const float* __restrict__ wh2,
                       const float* __restrict__ m2g, float* __restrict__ accP,
                       float* __restrict__ zP) {
  int bx = blockIdx.x;
  int js = bx & (JS - 1), rb = bx >> 3;
  int i0 = rb * 128;
  int jbase = js * STRIP;
  int tid = threadIdx.x;
  int w = tid >> 6, l = tid & 63, lr = l & 31, hi = l >> 5;

  __shared__ int adjL[2][128][36];          // pad 36: conflict-free b128 quads
  __shared__ f16 PL[2][4][2][2][32][8];     // [buf][rgg][kb][hfrag][lr][e]
  __shared__ float w2L[STRIP];

  // producer identity: this lane generates P for block-local row rloc
  int rloc = w * 32 + lr;
  float M2 = m2g[0];
  float w1 = wh1[i0 + rloc];
  float mrow = lrelu(w1 + M2);

  // stage w2 strip
  *(f32x4*)(&w2L[tid * 4]) = *(const f32x4*)(wh2 + jbase + tid * 4);

  // adj stage addressing: thread -> (row sr, 16-int half jh)
  int sr = tid >> 1, jh = tid & 1;
  const int* aSrc = adj + (size_t)(i0 + sr) * NN + jbase + 16 * jh;

  i32x4 R[4];
#pragma unroll
  for (int q = 0; q < 4; ++q)
    R[q] = __builtin_nontemporal_load((const i32x4*)(aSrc + 4 * q));  // adj(0)

  f32x16 acc[4][2] = {};
  float zacc = 0.f;

  // ---- producer lambda: gen P(step) from adjL[ab] into PL[pb]
  auto genP = [&](int step, int ab, int pb) {
    i32x4 av[4];
    f32x4 wv[4];
#pragma unroll
    for (int q = 0; q < 4; ++q) {
      av[q] = *(const i32x4*)(&adjL[ab][rloc][16 * hi + 4 * q]);
      wv[q] = *(const f32x4*)(&w2L[step * 32 + 16 * hi + 4 * q]);
    }
    f16x8 pk[2];
#pragma unroll
    for (int q = 0; q < 4; ++q)
#pragma unroll
      for (int e = 0; e < 4; ++e) {
        float s = w1 + wv[q][e];
        float sc = fmaxf(s, 0.2f * s);
        float p = (av[q][e] > 0) ? __expf(sc - mrow) : 0.f;
        zacc += p;
        pk[q >> 1][(q & 1) * 4 + e] = (f16)p;
      }
    *(f16x8*)(&PL[pb][w][hi][0][lr][0]) = pk[0];
    *(f16x8*)(&PL[pb][w][hi][1][lr][0]) = pk[1];
  };

  // prologue
#pragma unroll
  for (int q = 0; q < 4; ++q) *(i32x4*)(&adjL[0][sr][16 * jh + 4 * q]) = R[q];
#pragma unroll
  for (int q = 0; q < 4; ++q)
    R[q] = __builtin_nontemporal_load((const i32x4*)(aSrc + 32 + 4 * q));  // adj(1)
  __syncthreads();
  genP(0, 0, 0);
  __syncthreads();

  const size_t jb0 = ((size_t)jbase >> 4) * 256 * 16;  // f16 offset of strip
  const f16* bPB = whT16 + jb0 + (size_t)(w * 64 + lr) * 16 + hi * 8;

  int cur = 0, ab = 1;
#pragma unroll 1
  for (int t = 0; t < NSTEP; ++t) {
    // B loads for step t: contiguous 1KB per instruction
    f16x8 bf[2][2];
#pragma unroll
    for (int kb = 0; kb < 2; ++kb)
#pragma unroll
      for (int ct = 0; ct < 2; ++ct)
        bf[kb][ct] = *(const f16x8*)(bPB + ((size_t)(2 * t + kb) * 256 + ct * 32) * 16);

    // write adj(t+1) (loaded last iter) into adjL[ab]
#pragma unroll
    for (int q = 0; q < 4; ++q) *(i32x4*)(&adjL[ab][sr][16 * jh + 4 * q]) = R[q];

    // issue adj(t+2)
    int tpre = (t + 2 < NSTEP) ? t + 2 : NSTEP - 1;
#pragma unroll
    for (int q = 0; q < 4; ++q)
      R[q] = __builtin_nontemporal_load((const i32x4*)(aSrc + tpre * 32 + 4 * q));

    // MFMA phase: A-fragments from PL[cur]
#pragma unroll
    for (int rgg = 0; rgg < 4; ++rgg) {
      f16x8 a0 = *(const f16x8*)(&PL[cur][rgg][0][hi][lr][0]);
      f16x8 a1 = *(const f16x8*)(&PL[cur][rgg][1][hi][lr][0]);
#pragma unroll
      for (int ct = 0; ct < 2; ++ct) {
        acc[rgg][ct] = __builtin_amdgcn_mfma_f32_32x32x16_f16(a0, bf[0][ct], acc[rgg][ct], 0, 0, 0);
        acc[rgg][ct] = __builtin_amdgcn_mfma_f32_32x32x16_f16(a1, bf[1][ct], acc[rgg][ct], 0, 0, 0);
      }
    }
    __syncthreads();
    if (t + 1 < NSTEP) genP(t + 1, ab, cur ^ 1);
    __syncthreads();
    cur ^= 1;
    ab ^= 1;
  }

  // Z: lane(lr,hi=0/1) hold complementary j-halves of row rloc
  zacc += __shfl_xor(zacc, 32);
  if (hi == 0) zP[(size_t)js * NN + i0 + rloc] = zacc;

  // partial accumulator out. C/D: col=lane&31, row=(r&3)+8*(r>>2)+4*hi
  float* ap = accP + (size_t)js * NN * FOUT;
#pragma unroll
  for (int rgg = 0; rgg < 4; ++rgg)
#pragma unroll
    for (int ct = 0; ct < 2; ++ct)
#pragma unroll
      for (int r = 0; r < 16; ++r) {
        int grow = i0 + rgg * 32 + (r & 3) + 8 * (r >> 2) + 4 * hi;
        int gcol = w * 64 + ct * 32 + lr;
        __builtin_nontemporal_store(acc[rgg][ct][r], ap + (size_t)grow * FOUT + gcol);
      }
}

// ---- combine JS partials, divide by Z, elu
__global__ void k_combine(const float* __restrict__ accP, const float* __restrict__ zP,
                          float* __restrict__ out) {
  int id = blockIdx.x * 256 + threadIdx.x;
  size_t idx = (size_t)id * 4;
  int row = (int)(idx >> 8);
  f32x4 s = {};
#pragma unroll
  for (int p = 0; p < JS; ++p) {
    f32x4 v = __builtin_nontemporal_load((const f32x4*)(accP + (size_t)p * NN * FOUT + idx));
    s[0] += v[0]; s[1] += v[1]; s[2] += v[2]; s[3] += v[3];
  }
  float z = 0.f;
#pragma unroll
  for (int p = 0; p < JS; ++p) z += zP[(size_t)p * NN + row];
  float inv = (z > 0.f) ? 1.f / z : 0.f;
  f32x4 o;
#pragma unroll
  for (int i = 0; i < 4; ++i) {
    float x = s[i] * inv;
    o[i] = (x > 0.f) ? x : expm1f(x);
  }
  *(f32x4*)(out + idx) = o;
}

extern "C" void kernel_launch(void* const* d_in, const int* in_sizes, int n_in,
                              void* d_out, int out_size, void* d_ws, size_t ws_size,
                              hipStream_t stream) {
  const float* h = (const float*)d_in[0];
  const int* adj = (const int*)d_in[1];
  const float* W = (const float*)d_in[2];
  const float* a = (const float*)d_in[3];
  (void)in_sizes; (void)n_in; (void)out_size; (void)ws_size;

  char* ws = (char*)d_ws;
  size_t off = 0;
  auto alloc = [&](size_t bytes) {
    void* p = ws + off;
    off = (off + bytes + 255) & ~(size_t)255;
    return p;
  };
  float* accP = (float*)alloc((size_t)JS * NN * FOUT * 4);  // 64 MB
  f16* whT16 = (f16*)alloc((size_t)FOUT * NN * 2);
  float* wh1 = (float*)alloc((size_t)NN * 4);
  float* wh2 = (float*)alloc((size_t)NN * 4);
  float* m2 = (float*)alloc(256);
  float* zP = (float*)alloc((size_t)JS * NN * 4);
  // aliased prep buffers (lifetime ends when k_gemm1 completes)
  char* pb = (char*)accP;
  f16* hh = (f16*)pb;
  f16* hl = (f16*)(pb + (size_t)NN * FIN * 2);
  f16* wth = (f16*)(pb + (size_t)NN * FIN * 4);
  f16* wtl = (f16*)(pb + (size_t)NN * FIN * 4 + (size_t)FOUT * FIN * 2);

  k_prep_h<<<NN * FIN / 1024, 256, 0, stream>>>(h, hh, hl);
  k_prep_w<<<FIN * FOUT / 256, 256, 0, stream>>>(W, wth, wtl);
  k_gemm1<<<NN / 32, 256, 0, stream>>>(hh, hl, wth, wtl, a, whT16, wh1, wh2);
  k_max2<<<1, 256, 0, stream>>>(wh2, m2);
  k_attn<<<(NN / 128) * JS, 256, 0, stream>>>(adj, whT16, wh1, wh2, m2, accP, zP);
  k_combine<<<NN * FOUT / 1024, 256, 0, stream>>>(accP, zP, (float*)d_out);
}